// Round 1
// baseline (1899.985 us; speedup 1.0000x reference)
//
#include <hip/hip_runtime.h>
#include <math.h>

#define NEG_SLOPE 0.2f

__device__ __forceinline__ float lrelu(float x){ return x > 0.f ? x : NEG_SLOPE * x; }

// ---------------- CSR build (dst-indexed) ----------------
__global__ void k_count(const int* __restrict__ dst, int* __restrict__ cnt, int E){
  int e = blockIdx.x*blockDim.x + threadIdx.x;
  if (e < E) atomicAdd(&cnt[dst[e]], 1);
}

__global__ void k_exscan(const int* __restrict__ cnt, int* __restrict__ row, int n){
  __shared__ int buf[256];
  __shared__ int carry;
  int t = threadIdx.x;
  if (t == 0){ carry = 0; row[0] = 0; }
  __syncthreads();
  for (int base = 0; base < n; base += 256){
    int v = (base + t < n) ? cnt[base + t] : 0;
    buf[t] = v;
    __syncthreads();
    #pragma unroll
    for (int off = 1; off < 256; off <<= 1){
      int u = (t >= off) ? buf[t - off] : 0;
      __syncthreads();
      buf[t] += u;
      __syncthreads();
    }
    if (base + t < n) row[base + t + 1] = carry + buf[t];
    __syncthreads();
    if (t == 0) carry += buf[255];
    __syncthreads();
  }
}

__global__ void k_scatter(const int* __restrict__ src, const int* __restrict__ dst,
                          const int* __restrict__ row, int* __restrict__ cur,
                          int* __restrict__ csr, int E){
  int e = blockIdx.x*blockDim.x + threadIdx.x;
  if (e < E){
    int d = dst[e];
    int p = atomicAdd(&cur[d], 1);
    csr[row[d] + p] = src[e];
  }
}

// ---------------- fp32 tiled GEMM: C[M,N] = A[M,K] @ B[K,N] ----------------
template<int BM, int BN, int BK>
__global__ void k_gemm(const float* __restrict__ A, const float* __restrict__ B,
                       float* __restrict__ C, int M, int N, int K){
  __shared__ float As[BK][BM + 1];
  __shared__ float Bs[BK][BN + 1];
  int tid = threadIdx.x;            // 256 threads
  int tm = tid >> 4, tn = tid & 15; // 16x16 thread grid, 4x4 each
  int bm = blockIdx.y * BM, bn = blockIdx.x * BN;
  float acc[4][4] = {};
  for (int k0 = 0; k0 < K; k0 += BK){
    for (int i = tid; i < BM * BK; i += 256){
      int r = i / BK, c = i % BK;
      int gr = bm + r;
      As[c][r] = (gr < M) ? A[(long)gr * K + k0 + c] : 0.f;
    }
    for (int i = tid; i < BK * BN; i += 256){
      int r = i / BN, c = i % BN;
      Bs[r][c] = B[(long)(k0 + r) * N + bn + c];
    }
    __syncthreads();
    #pragma unroll
    for (int k = 0; k < BK; ++k){
      float a[4], b[4];
      #pragma unroll
      for (int i = 0; i < 4; ++i) a[i] = As[k][tm * 4 + i];
      #pragma unroll
      for (int j = 0; j < 4; ++j) b[j] = Bs[k][tn * 4 + j];
      #pragma unroll
      for (int i = 0; i < 4; ++i)
        #pragma unroll
        for (int j = 0; j < 4; ++j)
          acc[i][j] = fmaf(a[i], b[j], acc[i][j]);
    }
    __syncthreads();
  }
  #pragma unroll
  for (int i = 0; i < 4; ++i){
    int gr = bm + tm * 4 + i;
    if (gr < M){
      #pragma unroll
      for (int j = 0; j < 4; ++j)
        C[(long)gr * N + bn + tn * 4 + j] = acc[i][j];
    }
  }
}

// ---------------- attention logits: al_s/al_d [N,H] ----------------
template<int HEADS>
__global__ void k_logits(const float* __restrict__ hp, const float* __restrict__ a_s,
                         const float* __restrict__ a_d, float* __restrict__ al_s,
                         float* __restrict__ al_d, int N){
  int n = blockIdx.x;
  int t = threadIdx.x;           // HEADS*32
  int h = t >> 5, lane = t & 31;
  const float4 hv = *reinterpret_cast<const float4*>(hp + ((long)n * HEADS + h) * 128 + lane * 4);
  const float4 s4 = *reinterpret_cast<const float4*>(a_s + h * 128 + lane * 4);
  const float4 d4 = *reinterpret_cast<const float4*>(a_d + h * 128 + lane * 4);
  float ss = hv.x*s4.x + hv.y*s4.y + hv.z*s4.z + hv.w*s4.w;
  float sd = hv.x*d4.x + hv.y*d4.y + hv.z*d4.z + hv.w*d4.w;
  #pragma unroll
  for (int off = 16; off >= 1; off >>= 1){
    ss += __shfl_xor(ss, off);
    sd += __shfl_xor(sd, off);
  }
  if (lane == 0){
    al_s[(long)n * HEADS + h] = ss;
    al_d[(long)n * HEADS + h] = sd;
  }
}

// ---------------- GAT aggregation: online segment softmax + weighted sum ----------------
template<int HEADS, int VEC>
__global__ void k_gat(const float* __restrict__ hp, const float* __restrict__ al_s,
                      const float* __restrict__ al_d, const int* __restrict__ row,
                      const int* __restrict__ csr, const float* __restrict__ bias,
                      float* __restrict__ out, int N, int do_relu){
  constexpr int TPH = 128 / VEC;     // threads per head
  int n = blockIdx.x;
  int t = threadIdx.x;               // HEADS * TPH
  int h = t / TPH;
  int c0 = (t % TPH) * VEC;
  float ald = al_d[(long)n * HEADS + h];
  // self-loop as the initial online-softmax term (weight exp(0)=1)
  float m = lrelu(al_s[(long)n * HEADS + h] + ald);
  float l = 1.f;
  float acc[VEC];
  const float* hpn = hp + ((long)n * HEADS + h) * 128 + c0;
  if constexpr (VEC == 4){
    float4 hv = *reinterpret_cast<const float4*>(hpn);
    acc[0] = hv.x; acc[1] = hv.y; acc[2] = hv.z; acc[3] = hv.w;
  } else {
    float2 hv = *reinterpret_cast<const float2*>(hpn);
    acc[0] = hv.x; acc[1] = hv.y;
  }
  int beg = row[n], end = row[n + 1];
  for (int j = beg; j < end; ++j){
    int s = csr[j];
    float e = lrelu(al_s[(long)s * HEADS + h] + ald);
    float mn = fmaxf(m, e);
    float scale = __expf(m - mn);
    float p = __expf(e - mn);
    const float* hps = hp + ((long)s * HEADS + h) * 128 + c0;
    if constexpr (VEC == 4){
      float4 hv = *reinterpret_cast<const float4*>(hps);
      acc[0] = acc[0]*scale + p*hv.x;
      acc[1] = acc[1]*scale + p*hv.y;
      acc[2] = acc[2]*scale + p*hv.z;
      acc[3] = acc[3]*scale + p*hv.w;
    } else {
      float2 hv = *reinterpret_cast<const float2*>(hps);
      acc[0] = acc[0]*scale + p*hv.x;
      acc[1] = acc[1]*scale + p*hv.y;
    }
    l = l*scale + p;
    m = mn;
  }
  float inv = 1.f / l;
  #pragma unroll
  for (int v = 0; v < VEC; ++v){
    float o = acc[v]*inv + bias[h * 128 + c0 + v];
    if (do_relu) o = fmaxf(o, 0.f);
    out[((long)n * HEADS + h) * 128 + c0 + v] = o;
  }
}

// ---------------- MLP scorer: [B,256] -> 128 -> 64 -> 1 -> sigmoid ----------------
__global__ void k_mlp(const float* __restrict__ h3, const int* __restrict__ liq,
                      const int* __restrict__ ing,
                      const float* __restrict__ mw1, const float* __restrict__ mb1,
                      const float* __restrict__ mw2, const float* __restrict__ mb2,
                      const float* __restrict__ mw3, const float* __restrict__ mb3,
                      float* __restrict__ out, int B){
  __shared__ float pairv[256];
  __shared__ float z1[128];
  __shared__ float z2[64];
  int r = blockIdx.x;
  int t = threadIdx.x; // 128
  pairv[t]       = h3[(long)liq[r] * 128 + t];
  pairv[128 + t] = h3[(long)ing[r] * 128 + t];
  __syncthreads();
  float a1 = mb1[t];
  for (int k = 0; k < 256; ++k) a1 = fmaf(pairv[k], mw1[k * 128 + t], a1);
  z1[t] = fmaxf(a1, 0.f);
  __syncthreads();
  if (t < 64){
    float a2 = mb2[t];
    for (int k = 0; k < 128; ++k) a2 = fmaf(z1[k], mw2[k * 64 + t], a2);
    z2[t] = fmaxf(a2, 0.f);
  }
  __syncthreads();
  if (t < 64){
    float p = z2[t] * mw3[t];
    #pragma unroll
    for (int off = 32; off >= 1; off >>= 1) p += __shfl_xor(p, off);
    if (t == 0) out[r] = 1.f / (1.f + __expf(-(p + mb3[0])));
  }
}

// ---------------- launch ----------------
extern "C" void kernel_launch(void* const* d_in, const int* in_sizes, int n_in,
                              void* d_out, int out_size, void* d_ws, size_t ws_size,
                              hipStream_t stream){
  const float* x   = (const float*)d_in[0];
  const int*   ei  = (const int*)  d_in[1];
  const int*   liq = (const int*)  d_in[2];
  const int*   ing = (const int*)  d_in[3];
  const float* W1  = (const float*)d_in[4];
  const float* as1 = (const float*)d_in[5];
  const float* ad1 = (const float*)d_in[6];
  const float* b1  = (const float*)d_in[7];
  const float* W2  = (const float*)d_in[8];
  const float* as2 = (const float*)d_in[9];
  const float* ad2 = (const float*)d_in[10];
  const float* b2  = (const float*)d_in[11];
  const float* W3  = (const float*)d_in[12];
  const float* as3 = (const float*)d_in[13];
  const float* ad3 = (const float*)d_in[14];
  const float* b3  = (const float*)d_in[15];
  const float* mw1 = (const float*)d_in[16];
  const float* mb1 = (const float*)d_in[17];
  const float* mw2 = (const float*)d_in[18];
  const float* mb2 = (const float*)d_in[19];
  const float* mw3 = (const float*)d_in[20];
  const float* mb3 = (const float*)d_in[21];
  float* out = (float*)d_out;

  const int N = in_sizes[0] / 64;      // 25000
  const int E = in_sizes[1] / 2;       // 200000
  const int B = in_sizes[2];           // 4096
  const int* srcp = ei;
  const int* dstp = ei + E;

  // workspace carve-up
  char* w = (char*)d_ws;
  auto alloc = [&](size_t bytes) -> char* {
    char* p = w;
    w += (bytes + 255) & ~(size_t)255;
    return p;
  };
  float* P    = (float*)alloc((size_t)N * 1024 * 4);  // projected features
  float* Hb   = (float*)alloc((size_t)N * 1024 * 4);  // node features
  float* ALS  = (float*)alloc((size_t)N * 8 * 4);
  float* ALD  = (float*)alloc((size_t)N * 8 * 4);
  int*   row  = (int*)  alloc((size_t)(N + 1) * 4);
  int*   cnt  = (int*)  alloc((size_t)N * 4);
  int*   cur  = (int*)  alloc((size_t)N * 4);
  int*   csr  = (int*)  alloc((size_t)E * 4);
  (void)ws_size; (void)n_in; (void)out_size;

  // CSR build (same for all 3 layers)
  hipMemsetAsync(cnt, 0, (size_t)N * 4, stream);
  hipMemsetAsync(cur, 0, (size_t)N * 4, stream);
  int eb = (E + 255) / 256;
  k_count<<<eb, 256, 0, stream>>>(dstp, cnt, E);
  k_exscan<<<1, 256, 0, stream>>>(cnt, row, N);
  k_scatter<<<eb, 256, 0, stream>>>(srcp, dstp, row, cur, csr, E);

  const int mt = (N + 63) / 64;

  // ---- layer 1: x[N,64] @ W1[64,1024] ----
  k_gemm<64,64,16><<<dim3(1024/64, mt), 256, 0, stream>>>(x, W1, P, N, 1024, 64);
  k_logits<8><<<N, 256, 0, stream>>>(P, as1, ad1, ALS, ALD, N);
  k_gat<8,4><<<N, 256, 0, stream>>>(P, ALS, ALD, row, csr, b1, Hb, N, 1);

  // ---- layer 2: Hb[N,1024] @ W2[1024,1024] ----
  k_gemm<64,64,16><<<dim3(1024/64, mt), 256, 0, stream>>>(Hb, W2, P, N, 1024, 1024);
  k_logits<8><<<N, 256, 0, stream>>>(P, as2, ad2, ALS, ALD, N);
  k_gat<8,4><<<N, 256, 0, stream>>>(P, ALS, ALD, row, csr, b2, Hb, N, 1);

  // ---- layer 3: Hb[N,1024] @ W3[1024,128] (1 head) ----
  k_gemm<64,64,16><<<dim3(128/64, mt), 256, 0, stream>>>(Hb, W3, P, N, 128, 1024);
  k_logits<1><<<N, 32, 0, stream>>>(P, as3, ad3, ALS, ALD, N);
  k_gat<1,2><<<N, 64, 0, stream>>>(P, ALS, ALD, row, csr, b3, Hb, N, 0);

  // ---- MLP scorer ----
  k_mlp<<<B, 128, 0, stream>>>(Hb, liq, ing, mw1, mb1, mw2, mb2, mw3, mb3, out, B);
}

// Round 2
// 645.595 us; speedup vs baseline: 2.9430x; 2.9430x over previous
//
#include <hip/hip_runtime.h>
#include <math.h>

#define NEG_SLOPE 0.2f

typedef short short8 __attribute__((ext_vector_type(8)));
typedef float f32x4 __attribute__((ext_vector_type(4)));

__device__ __forceinline__ float lrelu(float x){ return x > 0.f ? x : NEG_SLOPE * x; }

__device__ __forceinline__ unsigned short f2bf(float f){
  union { float f; unsigned u; } v; v.f = f;
  unsigned r = v.u + 0x7fff + ((v.u >> 16) & 1);  // RNE
  return (unsigned short)(r >> 16);
}

// ---------------- CSR build (dst-indexed) ----------------
__global__ void k_count(const int* __restrict__ dst, int* __restrict__ cnt, int E){
  int e = blockIdx.x*blockDim.x + threadIdx.x;
  if (e < E) atomicAdd(&cnt[dst[e]], 1);
}

__global__ void k_exscan(const int* __restrict__ cnt, int* __restrict__ row, int n){
  __shared__ int buf[256];
  __shared__ int carry;
  int t = threadIdx.x;
  if (t == 0){ carry = 0; row[0] = 0; }
  __syncthreads();
  for (int base = 0; base < n; base += 256){
    int v = (base + t < n) ? cnt[base + t] : 0;
    buf[t] = v;
    __syncthreads();
    #pragma unroll
    for (int off = 1; off < 256; off <<= 1){
      int u = (t >= off) ? buf[t - off] : 0;
      __syncthreads();
      buf[t] += u;
      __syncthreads();
    }
    if (base + t < n) row[base + t + 1] = carry + buf[t];
    __syncthreads();
    if (t == 0) carry += buf[255];
    __syncthreads();
  }
}

__global__ void k_scatter(const int* __restrict__ src, const int* __restrict__ dst,
                          const int* __restrict__ row, int* __restrict__ cur,
                          int* __restrict__ csr, int E){
  int e = blockIdx.x*blockDim.x + threadIdx.x;
  if (e < E){
    int d = dst[e];
    int p = atomicAdd(&cur[d], 1);
    csr[row[d] + p] = src[e];
  }
}

// ---------------- conversions ----------------
__global__ void k_f2bf(const float* __restrict__ in, unsigned short* __restrict__ out, int n){
  int i = blockIdx.x*blockDim.x + threadIdx.x;
  if (i < n) out[i] = f2bf(in[i]);
}

// W[K,N] fp32 -> Wt[N,K] bf16
__global__ void k_transpose_bf16(const float* __restrict__ W, unsigned short* __restrict__ Wt,
                                 int K, int N){
  __shared__ float tile[32][33];
  int kb = blockIdx.x * 32, nb = blockIdx.y * 32;
  int tx = threadIdx.x & 31, ty = threadIdx.x >> 5;  // 256 threads: 32x8
  #pragma unroll
  for (int i = ty; i < 32; i += 8) tile[i][tx] = W[(size_t)(kb + i) * N + nb + tx];
  __syncthreads();
  #pragma unroll
  for (int i = ty; i < 32; i += 8) Wt[(size_t)(nb + i) * K + kb + tx] = f2bf(tile[tx][i]);
}

// ---------------- bf16 MFMA GEMM: C[M,N] = A[M,K] @ Bt[N,K]^T ----------------
// 128x128 tile, 4 waves, each wave 64x64 (4x4 frags of 16x16x32 MFMA)
__global__ __launch_bounds__(256) void k_gemm_bf16(
    const unsigned short* __restrict__ A,   // [M,K] bf16
    const unsigned short* __restrict__ Bt,  // [N,K] bf16 (pre-transposed B)
    float* __restrict__ C, int M, int N, int K){
  __shared__ unsigned short As[128 * 40];  // pad stride 40 shorts = 80B (16B-aligned rows)
  __shared__ unsigned short Bs[128 * 40];
  const int tid  = threadIdx.x;
  const int lane = tid & 63, wave = tid >> 6;
  const int wr = wave >> 1, wc = wave & 1;
  const int bm = blockIdx.y * 128, bn = blockIdx.x * 128;
  const int lr = lane & 15, lk = lane >> 4;
  const int ar = tid >> 2;            // staging row within 64-row round
  const int ac = (tid & 3) * 8;       // staging k-col
  f32x4 acc[4][4] = {};
  for (int k0 = 0; k0 < K; k0 += 32){
    #pragma unroll
    for (int r = 0; r < 2; ++r){
      int arow = r * 64 + ar;
      int gr = bm + arow; if (gr >= M) gr = M - 1;
      *reinterpret_cast<short8*>(&As[arow * 40 + ac]) =
        *reinterpret_cast<const short8*>(&A[(size_t)gr * K + k0 + ac]);
      *reinterpret_cast<short8*>(&Bs[arow * 40 + ac]) =
        *reinterpret_cast<const short8*>(&Bt[(size_t)(bn + arow) * K + k0 + ac]);
    }
    __syncthreads();
    short8 af[4], bg[4];
    #pragma unroll
    for (int m = 0; m < 4; ++m)
      af[m] = *reinterpret_cast<const short8*>(&As[(wr * 64 + m * 16 + lr) * 40 + lk * 8]);
    #pragma unroll
    for (int n = 0; n < 4; ++n)
      bg[n] = *reinterpret_cast<const short8*>(&Bs[(wc * 64 + n * 16 + lr) * 40 + lk * 8]);
    #pragma unroll
    for (int m = 0; m < 4; ++m)
      #pragma unroll
      for (int n = 0; n < 4; ++n)
        acc[m][n] = __builtin_amdgcn_mfma_f32_16x16x32_bf16(af[m], bg[n], acc[m][n], 0, 0, 0);
    __syncthreads();
  }
  #pragma unroll
  for (int m = 0; m < 4; ++m){
    #pragma unroll
    for (int j = 0; j < 4; ++j){
      int row = bm + wr * 64 + m * 16 + lk * 4 + j;
      if (row < M){
        #pragma unroll
        for (int n = 0; n < 4; ++n)
          C[(size_t)row * N + bn + wc * 64 + n * 16 + lr] = acc[m][n][j];
      }
    }
  }
}

// ---------------- attention logits: al_s/al_d [N,H] ----------------
template<int HEADS>
__global__ void k_logits(const float* __restrict__ hp, const float* __restrict__ a_s,
                         const float* __restrict__ a_d, float* __restrict__ al_s,
                         float* __restrict__ al_d, int N){
  int n = blockIdx.x;
  int t = threadIdx.x;           // HEADS*32
  int h = t >> 5, lane = t & 31;
  const float4 hv = *reinterpret_cast<const float4*>(hp + ((long)n * HEADS + h) * 128 + lane * 4);
  const float4 s4 = *reinterpret_cast<const float4*>(a_s + h * 128 + lane * 4);
  const float4 d4 = *reinterpret_cast<const float4*>(a_d + h * 128 + lane * 4);
  float ss = hv.x*s4.x + hv.y*s4.y + hv.z*s4.z + hv.w*s4.w;
  float sd = hv.x*d4.x + hv.y*d4.y + hv.z*d4.z + hv.w*d4.w;
  #pragma unroll
  for (int off = 16; off >= 1; off >>= 1){
    ss += __shfl_xor(ss, off);
    sd += __shfl_xor(sd, off);
  }
  if (lane == 0){
    al_s[(long)n * HEADS + h] = ss;
    al_d[(long)n * HEADS + h] = sd;
  }
}

// ---------------- GAT aggregation: online segment softmax + weighted sum ----------------
// OUTBF=1: write bf16 (feeds next GEMM); OUTBF=0: write fp32
template<int HEADS, int VEC, int OUTBF>
__global__ void k_gat(const float* __restrict__ hp, const float* __restrict__ al_s,
                      const float* __restrict__ al_d, const int* __restrict__ row,
                      const int* __restrict__ csr, const float* __restrict__ bias,
                      void* __restrict__ outv, int N, int do_relu){
  constexpr int TPH = 128 / VEC;
  int n = blockIdx.x;
  int t = threadIdx.x;               // HEADS * TPH
  int h = t / TPH;
  int c0 = (t % TPH) * VEC;
  float ald = al_d[(long)n * HEADS + h];
  float m = lrelu(al_s[(long)n * HEADS + h] + ald);  // self-loop init
  float l = 1.f;
  float acc[VEC];
  const float* hpn = hp + ((long)n * HEADS + h) * 128 + c0;
  if constexpr (VEC == 4){
    float4 hv = *reinterpret_cast<const float4*>(hpn);
    acc[0] = hv.x; acc[1] = hv.y; acc[2] = hv.z; acc[3] = hv.w;
  } else {
    float2 hv = *reinterpret_cast<const float2*>(hpn);
    acc[0] = hv.x; acc[1] = hv.y;
  }
  int beg = row[n], end = row[n + 1];
  for (int j = beg; j < end; ++j){
    int s = csr[j];
    float e = lrelu(al_s[(long)s * HEADS + h] + ald);
    float mn = fmaxf(m, e);
    float scale = __expf(m - mn);
    float p = __expf(e - mn);
    const float* hps = hp + ((long)s * HEADS + h) * 128 + c0;
    if constexpr (VEC == 4){
      float4 hv = *reinterpret_cast<const float4*>(hps);
      acc[0] = acc[0]*scale + p*hv.x;
      acc[1] = acc[1]*scale + p*hv.y;
      acc[2] = acc[2]*scale + p*hv.z;
      acc[3] = acc[3]*scale + p*hv.w;
    } else {
      float2 hv = *reinterpret_cast<const float2*>(hps);
      acc[0] = acc[0]*scale + p*hv.x;
      acc[1] = acc[1]*scale + p*hv.y;
    }
    l = l*scale + p;
    m = mn;
  }
  float inv = 1.f / l;
  size_t ob = ((size_t)n * HEADS + h) * 128 + c0;
  #pragma unroll
  for (int v = 0; v < VEC; ++v){
    float o = acc[v]*inv + bias[h * 128 + c0 + v];
    if (do_relu) o = fmaxf(o, 0.f);
    if constexpr (OUTBF) ((unsigned short*)outv)[ob + v] = f2bf(o);
    else                 ((float*)outv)[ob + v] = o;
  }
}

// ---------------- MLP scorer: [B,256] -> 128 -> 64 -> 1 -> sigmoid ----------------
__global__ void k_mlp(const float* __restrict__ h3, const int* __restrict__ liq,
                      const int* __restrict__ ing,
                      const float* __restrict__ mw1, const float* __restrict__ mb1,
                      const float* __restrict__ mw2, const float* __restrict__ mb2,
                      const float* __restrict__ mw3, const float* __restrict__ mb3,
                      float* __restrict__ out, int B){
  __shared__ float pairv[256];
  __shared__ float z1[128];
  __shared__ float z2[64];
  int r = blockIdx.x;
  int t = threadIdx.x; // 128
  pairv[t]       = h3[(long)liq[r] * 128 + t];
  pairv[128 + t] = h3[(long)ing[r] * 128 + t];
  __syncthreads();
  float a1 = mb1[t];
  for (int k = 0; k < 256; ++k) a1 = fmaf(pairv[k], mw1[k * 128 + t], a1);
  z1[t] = fmaxf(a1, 0.f);
  __syncthreads();
  if (t < 64){
    float a2 = mb2[t];
    for (int k = 0; k < 128; ++k) a2 = fmaf(z1[k], mw2[k * 64 + t], a2);
    z2[t] = fmaxf(a2, 0.f);
  }
  __syncthreads();
  if (t < 64){
    float p = z2[t] * mw3[t];
    #pragma unroll
    for (int off = 32; off >= 1; off >>= 1) p += __shfl_xor(p, off);
    if (t == 0) out[r] = 1.f / (1.f + __expf(-(p + mb3[0])));
  }
}

// ---------------- launch ----------------
extern "C" void kernel_launch(void* const* d_in, const int* in_sizes, int n_in,
                              void* d_out, int out_size, void* d_ws, size_t ws_size,
                              hipStream_t stream){
  const float* x   = (const float*)d_in[0];
  const int*   ei  = (const int*)  d_in[1];
  const int*   liq = (const int*)  d_in[2];
  const int*   ing = (const int*)  d_in[3];
  const float* W1  = (const float*)d_in[4];
  const float* as1 = (const float*)d_in[5];
  const float* ad1 = (const float*)d_in[6];
  const float* b1  = (const float*)d_in[7];
  const float* W2  = (const float*)d_in[8];
  const float* as2 = (const float*)d_in[9];
  const float* ad2 = (const float*)d_in[10];
  const float* b2  = (const float*)d_in[11];
  const float* W3  = (const float*)d_in[12];
  const float* as3 = (const float*)d_in[13];
  const float* ad3 = (const float*)d_in[14];
  const float* b3  = (const float*)d_in[15];
  const float* mw1 = (const float*)d_in[16];
  const float* mb1 = (const float*)d_in[17];
  const float* mw2 = (const float*)d_in[18];
  const float* mb2 = (const float*)d_in[19];
  const float* mw3 = (const float*)d_in[20];
  const float* mb3 = (const float*)d_in[21];
  float* out = (float*)d_out;

  const int N = in_sizes[0] / 64;      // 25000
  const int E = in_sizes[1] / 2;       // 200000
  const int B = in_sizes[2];           // 4096
  const int* srcp = ei;
  const int* dstp = ei + E;

  // workspace carve-up
  char* w = (char*)d_ws;
  auto alloc = [&](size_t bytes) -> char* {
    char* p = w;
    w += (bytes + 255) & ~(size_t)255;
    return p;
  };
  float*          P    = (float*)         alloc((size_t)N * 1024 * 4);  // GEMM out (fp32)
  unsigned short* Hb   = (unsigned short*)alloc((size_t)N * 1024 * 2);  // node feats bf16
  float*          H3   = (float*)         alloc((size_t)N * 128 * 4);   // layer-3 out fp32
  unsigned short* xb   = (unsigned short*)alloc((size_t)N * 64 * 2);
  unsigned short* Wt1  = (unsigned short*)alloc((size_t)1024 * 64 * 2);
  unsigned short* Wt2  = (unsigned short*)alloc((size_t)1024 * 1024 * 2);
  unsigned short* Wt3  = (unsigned short*)alloc((size_t)128 * 1024 * 2);
  float* ALS  = (float*)alloc((size_t)N * 8 * 4);
  float* ALD  = (float*)alloc((size_t)N * 8 * 4);
  int*   row  = (int*)  alloc((size_t)(N + 1) * 4);
  int*   cnt  = (int*)  alloc((size_t)N * 4);
  int*   cur  = (int*)  alloc((size_t)N * 4);
  int*   csr  = (int*)  alloc((size_t)E * 4);
  (void)ws_size; (void)n_in; (void)out_size;

  // conversions
  int nx = N * 64;
  k_f2bf<<<(nx + 255) / 256, 256, 0, stream>>>(x, xb, nx);
  k_transpose_bf16<<<dim3(64/32, 1024/32), 256, 0, stream>>>(W1, Wt1, 64, 1024);
  k_transpose_bf16<<<dim3(1024/32, 1024/32), 256, 0, stream>>>(W2, Wt2, 1024, 1024);
  k_transpose_bf16<<<dim3(1024/32, 128/32), 256, 0, stream>>>(W3, Wt3, 1024, 128);

  // CSR build
  hipMemsetAsync(cnt, 0, (size_t)N * 4, stream);
  hipMemsetAsync(cur, 0, (size_t)N * 4, stream);
  int eb = (E + 255) / 256;
  k_count<<<eb, 256, 0, stream>>>(dstp, cnt, E);
  k_exscan<<<1, 256, 0, stream>>>(cnt, row, N);
  k_scatter<<<eb, 256, 0, stream>>>(srcp, dstp, row, cur, csr, E);

  const int mt = (N + 127) / 128;

  // ---- layer 1: x[N,64] @ W1[64,1024] ----
  k_gemm_bf16<<<dim3(1024/128, mt), 256, 0, stream>>>(xb, Wt1, P, N, 1024, 64);
  k_logits<8><<<N, 256, 0, stream>>>(P, as1, ad1, ALS, ALD, N);
  k_gat<8,4,1><<<N, 256, 0, stream>>>(P, ALS, ALD, row, csr, b1, Hb, N, 1);

  // ---- layer 2: Hb[N,1024] @ W2[1024,1024] ----
  k_gemm_bf16<<<dim3(1024/128, mt), 256, 0, stream>>>(Hb, Wt2, P, N, 1024, 1024);
  k_logits<8><<<N, 256, 0, stream>>>(P, as2, ad2, ALS, ALD, N);
  k_gat<8,4,1><<<N, 256, 0, stream>>>(P, ALS, ALD, row, csr, b2, Hb, N, 1);

  // ---- layer 3: Hb[N,1024] @ W3[1024,128] (1 head) ----
  k_gemm_bf16<<<dim3(128/128, mt), 256, 0, stream>>>(Hb, Wt3, P, N, 128, 1024);
  k_logits<1><<<N, 32, 0, stream>>>(P, as3, ad3, ALS, ALD, N);
  k_gat<1,2,0><<<N, 64, 0, stream>>>(P, ALS, ALD, row, csr, b3, H3, N, 0);

  // ---- MLP scorer ----
  k_mlp<<<B, 128, 0, stream>>>(H3, liq, ing, mw1, mb1, mw2, mb2, mw3, mb3, out, B);
}

// Round 3
// 496.373 us; speedup vs baseline: 3.8277x; 1.3006x over previous
//
#include <hip/hip_runtime.h>
#include <math.h>

#define NEG_SLOPE 0.2f

typedef short short8 __attribute__((ext_vector_type(8)));
typedef float f32x4 __attribute__((ext_vector_type(4)));

__device__ __forceinline__ float lrelu(float x){ return x > 0.f ? x : NEG_SLOPE * x; }

__device__ __forceinline__ unsigned short f2bf(float f){
  union { float f; unsigned u; } v; v.f = f;
  unsigned r = v.u + 0x7fff + ((v.u >> 16) & 1);  // RNE
  return (unsigned short)(r >> 16);
}
__device__ __forceinline__ float bf2f(unsigned short u){
  union { unsigned u; float f; } v; v.u = ((unsigned)u) << 16; return v.f;
}

__device__ __forceinline__ void gld16(const unsigned short* g, unsigned short* l){
  __builtin_amdgcn_global_load_lds(
      (const __attribute__((address_space(1))) unsigned int*)g,
      (__attribute__((address_space(3))) unsigned int*)l, 16, 0, 0);
}

// ---------------- CSR build (dst-indexed) ----------------
__global__ void k_count(const int* __restrict__ dst, int* __restrict__ cnt, int E){
  int e = blockIdx.x*blockDim.x + threadIdx.x;
  if (e < E) atomicAdd(&cnt[dst[e]], 1);
}

__global__ void k_exscan(const int* __restrict__ cnt, int* __restrict__ row, int n){
  __shared__ int buf[256];
  __shared__ int carry;
  int t = threadIdx.x;
  if (t == 0){ carry = 0; row[0] = 0; }
  __syncthreads();
  for (int base = 0; base < n; base += 256){
    int v = (base + t < n) ? cnt[base + t] : 0;
    buf[t] = v;
    __syncthreads();
    #pragma unroll
    for (int off = 1; off < 256; off <<= 1){
      int u = (t >= off) ? buf[t - off] : 0;
      __syncthreads();
      buf[t] += u;
      __syncthreads();
    }
    if (base + t < n) row[base + t + 1] = carry + buf[t];
    __syncthreads();
    if (t == 0) carry += buf[255];
    __syncthreads();
  }
}

__global__ void k_scatter(const int* __restrict__ src, const int* __restrict__ dst,
                          const int* __restrict__ row, int* __restrict__ cur,
                          int* __restrict__ csr, int E){
  int e = blockIdx.x*blockDim.x + threadIdx.x;
  if (e < E){
    int d = dst[e];
    int p = atomicAdd(&cur[d], 1);
    csr[row[d] + p] = src[e];
  }
}

// ---------------- conversions ----------------
__global__ void k_f2bf(const float* __restrict__ in, unsigned short* __restrict__ out, int n){
  int i = blockIdx.x*blockDim.x + threadIdx.x;
  if (i < n) out[i] = f2bf(in[i]);
}

// W[K,N] fp32 -> Wt[N,K] bf16
__global__ void k_transpose_bf16(const float* __restrict__ W, unsigned short* __restrict__ Wt,
                                 int K, int N){
  __shared__ float tile[32][33];
  int kb = blockIdx.x * 32, nb = blockIdx.y * 32;
  int tx = threadIdx.x & 31, ty = threadIdx.x >> 5;  // 256 threads: 32x8
  #pragma unroll
  for (int i = ty; i < 32; i += 8) tile[i][tx] = W[(size_t)(kb + i) * N + nb + tx];
  __syncthreads();
  #pragma unroll
  for (int i = ty; i < 32; i += 8) Wt[(size_t)(nb + i) * K + kb + tx] = f2bf(tile[tx][i]);
}

// ---------------- bf16 MFMA GEMM (m97 structure): C[M,N](bf16) = A[M,K] @ Bt[N,K]^T ----
// 128x128 tile, 4 waves (2x2), 64x64 per wave, 16x16x32 MFMA, BK=32,
// global_load_lds width-16 staging into linear LDS [128][32].
__global__ __launch_bounds__(256) void k_gemm_bf16(
    const unsigned short* __restrict__ A,   // [M,K] bf16
    const unsigned short* __restrict__ Bt,  // [N,K] bf16
    unsigned short* __restrict__ C,         // [M,N] bf16
    int M, int N, int K){
  __shared__ unsigned short As[128 * 32];
  __shared__ unsigned short Bs[128 * 32];
  const int tid  = threadIdx.x;
  const int lane = tid & 63, wave = tid >> 6;
  const int wr = wave >> 1, wc = wave & 1;
  const int bm = blockIdx.y * 128, bn = blockIdx.x * 128;
  const int lr = lane & 15, lk = lane >> 4;
  // staging geometry: wave-uniform LDS base + lane*16B (HW rule).
  // round i (0,1): rows (wave + i*4)*16 + lane/4, k-col (lane&3)*8
  const int srow = wave * 16 + (lane >> 2);
  const int skc  = (lane & 3) * 8;
  int ar0 = bm + srow;      if (ar0 >= M) ar0 = M - 1;
  int ar1 = bm + srow + 64; if (ar1 >= M) ar1 = M - 1;
  const unsigned short* ga0 = A  + (size_t)ar0 * K + skc;
  const unsigned short* ga1 = A  + (size_t)ar1 * K + skc;
  const unsigned short* gb0 = Bt + (size_t)(bn + srow) * K + skc;
  const unsigned short* gb1 = Bt + (size_t)(bn + srow + 64) * K + skc;
  f32x4 acc[4][4] = {};
  for (int k0 = 0; k0 < K; k0 += 32){
    gld16(ga0 + k0, &As[(size_t)wave * 512]);
    gld16(ga1 + k0, &As[(size_t)(wave + 4) * 512]);
    gld16(gb0 + k0, &Bs[(size_t)wave * 512]);
    gld16(gb1 + k0, &Bs[(size_t)(wave + 4) * 512]);
    __syncthreads();
    short8 af[4], bg[4];
    #pragma unroll
    for (int m = 0; m < 4; ++m)
      af[m] = *reinterpret_cast<const short8*>(&As[(wr * 64 + m * 16 + lr) * 32 + lk * 8]);
    #pragma unroll
    for (int n = 0; n < 4; ++n)
      bg[n] = *reinterpret_cast<const short8*>(&Bs[(wc * 64 + n * 16 + lr) * 32 + lk * 8]);
    #pragma unroll
    for (int m = 0; m < 4; ++m)
      #pragma unroll
      for (int n = 0; n < 4; ++n)
        acc[m][n] = __builtin_amdgcn_mfma_f32_16x16x32_bf16(af[m], bg[n], acc[m][n], 0, 0, 0);
    __syncthreads();
  }
  #pragma unroll
  for (int m = 0; m < 4; ++m){
    #pragma unroll
    for (int j = 0; j < 4; ++j){
      int row = bm + wr * 64 + m * 16 + lk * 4 + j;
      if (row < M){
        #pragma unroll
        for (int n = 0; n < 4; ++n)
          C[(size_t)row * N + bn + wc * 64 + n * 16 + lr] = f2bf(acc[m][n][j]);
      }
    }
  }
}

// ---------------- attention logits from bf16 features ----------------
// block = HEADS*16*NPB threads; 16 lanes per (node,head), 8 elems each
template<int HEADS, int NPB>
__global__ void k_logits_bf(const unsigned short* __restrict__ hp, const float* __restrict__ a_s,
                            const float* __restrict__ a_d, float* __restrict__ al_s,
                            float* __restrict__ al_d, int N){
  int t = threadIdx.x;
  int node = blockIdx.x * NPB + t / (HEADS * 16);
  if (node >= N) return;
  int r = t % (HEADS * 16);
  int h = r >> 4, lane = r & 15;
  short8 hv8 = *reinterpret_cast<const short8*>(hp + ((size_t)node * HEADS + h) * 128 + lane * 8);
  const float* as = a_s + h * 128 + lane * 8;
  const float* ad = a_d + h * 128 + lane * 8;
  float ss = 0.f, sd = 0.f;
  #pragma unroll
  for (int i = 0; i < 8; ++i){
    float hv = bf2f((unsigned short)hv8[i]);
    ss = fmaf(hv, as[i], ss);
    sd = fmaf(hv, ad[i], sd);
  }
  #pragma unroll
  for (int off = 8; off >= 1; off >>= 1){
    ss += __shfl_xor(ss, off);
    sd += __shfl_xor(sd, off);
  }
  if (lane == 0){
    al_s[(size_t)node * HEADS + h] = ss;
    al_d[(size_t)node * HEADS + h] = sd;
  }
}

// ---------------- GAT aggregation from bf16 features ----------------
template<int HEADS, int VEC, int OUTBF>
__global__ void k_gat_bf(const unsigned short* __restrict__ hp, const float* __restrict__ al_s,
                         const float* __restrict__ al_d, const int* __restrict__ row,
                         const int* __restrict__ csr, const float* __restrict__ bias,
                         void* __restrict__ outv, int N, int do_relu){
  constexpr int TPH = 128 / VEC;
  int n = blockIdx.x;
  int t = threadIdx.x;               // HEADS * TPH
  int h = t / TPH;
  int c0 = (t % TPH) * VEC;
  float ald = al_d[(size_t)n * HEADS + h];
  float m = lrelu(al_s[(size_t)n * HEADS + h] + ald);  // self-loop init (weight exp(0)=1)
  float l = 1.f;
  float acc[VEC];
  const unsigned short* hpn = hp + ((size_t)n * HEADS + h) * 128 + c0;
  if constexpr (VEC == 8){
    short8 hv8 = *reinterpret_cast<const short8*>(hpn);
    #pragma unroll
    for (int v = 0; v < 8; ++v) acc[v] = bf2f((unsigned short)hv8[v]);
  } else {
    ushort2 hv2 = *reinterpret_cast<const ushort2*>(hpn);
    acc[0] = bf2f(hv2.x); acc[1] = bf2f(hv2.y);
  }
  int beg = row[n], end = row[n + 1];
  for (int j = beg; j < end; ++j){
    int s = csr[j];
    float e = lrelu(al_s[(size_t)s * HEADS + h] + ald);
    float mn = fmaxf(m, e);
    float scale = __expf(m - mn);
    float p = __expf(e - mn);
    const unsigned short* hps = hp + ((size_t)s * HEADS + h) * 128 + c0;
    if constexpr (VEC == 8){
      short8 hv8 = *reinterpret_cast<const short8*>(hps);
      #pragma unroll
      for (int v = 0; v < 8; ++v) acc[v] = acc[v] * scale + p * bf2f((unsigned short)hv8[v]);
    } else {
      ushort2 hv2 = *reinterpret_cast<const ushort2*>(hps);
      acc[0] = acc[0] * scale + p * bf2f(hv2.x);
      acc[1] = acc[1] * scale + p * bf2f(hv2.y);
    }
    l = l * scale + p;
    m = mn;
  }
  float inv = 1.f / l;
  size_t ob = ((size_t)n * HEADS + h) * 128 + c0;
  #pragma unroll
  for (int v = 0; v < VEC; ++v){
    float o = acc[v] * inv + bias[h * 128 + c0 + v];
    if (do_relu) o = fmaxf(o, 0.f);
    if constexpr (OUTBF) ((unsigned short*)outv)[ob + v] = f2bf(o);
    else                 ((float*)outv)[ob + v] = o;
  }
}

// ---------------- MLP scorer: [B,256] -> 128 -> 64 -> 1 -> sigmoid ----------------
__global__ void k_mlp(const float* __restrict__ h3, const int* __restrict__ liq,
                      const int* __restrict__ ing,
                      const float* __restrict__ mw1, const float* __restrict__ mb1,
                      const float* __restrict__ mw2, const float* __restrict__ mb2,
                      const float* __restrict__ mw3, const float* __restrict__ mb3,
                      float* __restrict__ out, int B){
  __shared__ float pairv[256];
  __shared__ float z1[128];
  __shared__ float z2[64];
  int r = blockIdx.x;
  int t = threadIdx.x; // 128
  pairv[t]       = h3[(size_t)liq[r] * 128 + t];
  pairv[128 + t] = h3[(size_t)ing[r] * 128 + t];
  __syncthreads();
  float a1 = mb1[t];
  for (int k = 0; k < 256; ++k) a1 = fmaf(pairv[k], mw1[k * 128 + t], a1);
  z1[t] = fmaxf(a1, 0.f);
  __syncthreads();
  if (t < 64){
    float a2 = mb2[t];
    for (int k = 0; k < 128; ++k) a2 = fmaf(z1[k], mw2[k * 64 + t], a2);
    z2[t] = fmaxf(a2, 0.f);
  }
  __syncthreads();
  if (t < 64){
    float p = z2[t] * mw3[t];
    #pragma unroll
    for (int off = 32; off >= 1; off >>= 1) p += __shfl_xor(p, off);
    if (t == 0) out[r] = 1.f / (1.f + __expf(-(p + mb3[0])));
  }
}

// ---------------- launch ----------------
extern "C" void kernel_launch(void* const* d_in, const int* in_sizes, int n_in,
                              void* d_out, int out_size, void* d_ws, size_t ws_size,
                              hipStream_t stream){
  const float* x   = (const float*)d_in[0];
  const int*   ei  = (const int*)  d_in[1];
  const int*   liq = (const int*)  d_in[2];
  const int*   ing = (const int*)  d_in[3];
  const float* W1  = (const float*)d_in[4];
  const float* as1 = (const float*)d_in[5];
  const float* ad1 = (const float*)d_in[6];
  const float* b1  = (const float*)d_in[7];
  const float* W2  = (const float*)d_in[8];
  const float* as2 = (const float*)d_in[9];
  const float* ad2 = (const float*)d_in[10];
  const float* b2  = (const float*)d_in[11];
  const float* W3  = (const float*)d_in[12];
  const float* as3 = (const float*)d_in[13];
  const float* ad3 = (const float*)d_in[14];
  const float* b3  = (const float*)d_in[15];
  const float* mw1 = (const float*)d_in[16];
  const float* mb1 = (const float*)d_in[17];
  const float* mw2 = (const float*)d_in[18];
  const float* mb2 = (const float*)d_in[19];
  const float* mw3 = (const float*)d_in[20];
  const float* mb3 = (const float*)d_in[21];
  float* out = (float*)d_out;

  const int N = in_sizes[0] / 64;      // 25000
  const int E = in_sizes[1] / 2;       // 200000
  const int B = in_sizes[2];           // 4096
  const int* srcp = ei;
  const int* dstp = ei + E;

  // workspace carve-up
  char* w = (char*)d_ws;
  auto alloc = [&](size_t bytes) -> char* {
    char* p = w;
    w += (bytes + 255) & ~(size_t)255;
    return p;
  };
  unsigned short* P    = (unsigned short*)alloc((size_t)N * 1024 * 2);  // projected feats bf16
  unsigned short* Hb   = (unsigned short*)alloc((size_t)N * 1024 * 2);  // node feats bf16
  float*          H3   = (float*)         alloc((size_t)N * 128 * 4);   // layer-3 out fp32
  unsigned short* xb   = (unsigned short*)alloc((size_t)N * 64 * 2);
  unsigned short* Wt1  = (unsigned short*)alloc((size_t)1024 * 64 * 2);
  unsigned short* Wt2  = (unsigned short*)alloc((size_t)1024 * 1024 * 2);
  unsigned short* Wt3  = (unsigned short*)alloc((size_t)128 * 1024 * 2);
  float* ALS  = (float*)alloc((size_t)N * 8 * 4);
  float* ALD  = (float*)alloc((size_t)N * 8 * 4);
  int*   row  = (int*)  alloc((size_t)(N + 1) * 4);
  int*   cnt  = (int*)  alloc((size_t)N * 4);
  int*   cur  = (int*)  alloc((size_t)N * 4);
  int*   csr  = (int*)  alloc((size_t)E * 4);
  (void)ws_size; (void)n_in; (void)out_size;

  // conversions
  int nx = N * 64;
  k_f2bf<<<(nx + 255) / 256, 256, 0, stream>>>(x, xb, nx);
  k_transpose_bf16<<<dim3(64/32, 1024/32), 256, 0, stream>>>(W1, Wt1, 64, 1024);
  k_transpose_bf16<<<dim3(1024/32, 1024/32), 256, 0, stream>>>(W2, Wt2, 1024, 1024);
  k_transpose_bf16<<<dim3(1024/32, 128/32), 256, 0, stream>>>(W3, Wt3, 1024, 128);

  // CSR build
  hipMemsetAsync(cnt, 0, (size_t)N * 4, stream);
  hipMemsetAsync(cur, 0, (size_t)N * 4, stream);
  int eb = (E + 255) / 256;
  k_count<<<eb, 256, 0, stream>>>(dstp, cnt, E);
  k_exscan<<<1, 256, 0, stream>>>(cnt, row, N);
  k_scatter<<<eb, 256, 0, stream>>>(srcp, dstp, row, cur, csr, E);

  const int mt = (N + 127) / 128;

  // ---- layer 1: x[N,64] @ W1[64,1024] ----
  k_gemm_bf16<<<dim3(1024/128, mt), 256, 0, stream>>>(xb, Wt1, P, N, 1024, 64);
  k_logits_bf<8,2><<<(N + 1) / 2, 256, 0, stream>>>(P, as1, ad1, ALS, ALD, N);
  k_gat_bf<8,8,1><<<N, 128, 0, stream>>>(P, ALS, ALD, row, csr, b1, Hb, N, 1);

  // ---- layer 2: Hb[N,1024] @ W2[1024,1024] ----
  k_gemm_bf16<<<dim3(1024/128, mt), 256, 0, stream>>>(Hb, Wt2, P, N, 1024, 1024);
  k_logits_bf<8,2><<<(N + 1) / 2, 256, 0, stream>>>(P, as2, ad2, ALS, ALD, N);
  k_gat_bf<8,8,1><<<N, 128, 0, stream>>>(P, ALS, ALD, row, csr, b2, Hb, N, 1);

  // ---- layer 3: Hb[N,1024] @ W3[1024,128] (1 head) ----
  k_gemm_bf16<<<dim3(1, mt), 256, 0, stream>>>(Hb, Wt3, P, N, 128, 1024);
  k_logits_bf<1,16><<<(N + 15) / 16, 256, 0, stream>>>(P, as3, ad3, ALS, ALD, N);
  k_gat_bf<1,2,0><<<N, 64, 0, stream>>>(P, ALS, ALD, row, csr, b3, H3, N, 0);

  // ---- MLP scorer ----
  k_mlp<<<B, 128, 0, stream>>>(H3, liq, ing, mw1, mb1, mw2, mb2, mw3, mb3, out, B);
}

// Round 4
// 386.762 us; speedup vs baseline: 4.9125x; 1.2834x over previous
//
#include <hip/hip_runtime.h>
#include <math.h>

#define NEG_SLOPE 0.2f

typedef short short8 __attribute__((ext_vector_type(8)));
typedef float f32x4 __attribute__((ext_vector_type(4)));

__device__ __forceinline__ float lrelu(float x){ return x > 0.f ? x : NEG_SLOPE * x; }

__device__ __forceinline__ unsigned short f2bf(float f){
  union { float f; unsigned u; } v; v.f = f;
  unsigned r = v.u + 0x7fff + ((v.u >> 16) & 1);  // RNE
  return (unsigned short)(r >> 16);
}
__device__ __forceinline__ float bf2f(unsigned short u){
  union { unsigned u; float f; } v; v.u = ((unsigned)u) << 16; return v.f;
}

__device__ __forceinline__ void gld16(const unsigned short* g, unsigned short* l){
  __builtin_amdgcn_global_load_lds(
      (const __attribute__((address_space(1))) unsigned int*)g,
      (__attribute__((address_space(3))) unsigned int*)l, 16, 0, 0);
}

// ---------------- CSR build (dst-indexed) ----------------
__global__ void k_count(const int* __restrict__ dst, int* __restrict__ cnt, int E){
  int e = blockIdx.x*blockDim.x + threadIdx.x;
  if (e < E) atomicAdd(&cnt[dst[e]], 1);
}

// parallel 2-level scan: per-block inclusive scan + block sums
__global__ void k_blockscan(const int* __restrict__ cnt, int* __restrict__ row,
                            int* __restrict__ aux, int n){
  __shared__ int buf[256];
  int t = threadIdx.x;
  int base = blockIdx.x * 256;
  int v = (base + t < n) ? cnt[base + t] : 0;
  buf[t] = v;
  __syncthreads();
  #pragma unroll
  for (int off = 1; off < 256; off <<= 1){
    int u = (t >= off) ? buf[t - off] : 0;
    __syncthreads();
    buf[t] += u;
    __syncthreads();
  }
  if (base + t < n) row[base + t + 1] = buf[t];   // inclusive within block
  if (t == 255) aux[blockIdx.x] = buf[255];
  if (blockIdx.x == 0 && t == 0) row[0] = 0;
}

__global__ void k_scanaux(int* __restrict__ aux, int nb){  // nb <= 256, 1 block
  __shared__ int buf[256];
  int t = threadIdx.x;
  int v = (t < nb) ? aux[t] : 0;
  buf[t] = v;
  __syncthreads();
  #pragma unroll
  for (int off = 1; off < 256; off <<= 1){
    int u = (t >= off) ? buf[t - off] : 0;
    __syncthreads();
    buf[t] += u;
    __syncthreads();
  }
  if (t < nb) aux[t] = buf[t] - v;   // exclusive block offsets
}

__global__ void k_addoff(const int* __restrict__ aux, int* __restrict__ row, int n){
  int i = blockIdx.x*blockDim.x + threadIdx.x;
  if (i < n) row[i + 1] += aux[i >> 8];
}

__global__ void k_scatter(const int* __restrict__ src, const int* __restrict__ dst,
                          const int* __restrict__ row, int* __restrict__ cur,
                          int* __restrict__ csr, int E){
  int e = blockIdx.x*blockDim.x + threadIdx.x;
  if (e < E){
    int d = dst[e];
    int p = atomicAdd(&cur[d], 1);
    csr[row[d] + p] = src[e];
  }
}

// ---------------- conversions ----------------
__global__ void k_f2bf(const float* __restrict__ in, unsigned short* __restrict__ out, int n){
  int i = blockIdx.x*blockDim.x + threadIdx.x;
  if (i < n) out[i] = f2bf(in[i]);
}

// W[K,N] fp32 -> Wt[N,K] bf16
__global__ void k_transpose_bf16(const float* __restrict__ W, unsigned short* __restrict__ Wt,
                                 int K, int N){
  __shared__ float tile[32][33];
  int kb = blockIdx.x * 32, nb = blockIdx.y * 32;
  int tx = threadIdx.x & 31, ty = threadIdx.x >> 5;  // 256 threads: 32x8
  #pragma unroll
  for (int i = ty; i < 32; i += 8) tile[i][tx] = W[(size_t)(kb + i) * N + nb + tx];
  __syncthreads();
  #pragma unroll
  for (int i = ty; i < 32; i += 8) Wt[(size_t)(nb + i) * K + kb + tx] = f2bf(tile[tx][i]);
}

// ---------------- bf16 MFMA GEMM (m97 structure + XCD swizzle) ----------------
// C[M,N](bf16) = A[M,K] @ Bt[N,K]^T. 128x128 tile, 4 waves, 16x16x32 MFMA, BK=32.
// 1D grid of gxc*gyc blocks; chunked XCD swizzle when nwg%8==0.
__global__ __launch_bounds__(256) void k_gemm_bf16(
    const unsigned short* __restrict__ A,   // [M,K] bf16
    const unsigned short* __restrict__ Bt,  // [N,K] bf16
    unsigned short* __restrict__ C,         // [M,N] bf16
    int M, int N, int K, int gxc){
  __shared__ unsigned short As[128 * 32];
  __shared__ unsigned short Bs[128 * 32];
  const int nwg = gridDim.x;
  int bid = blockIdx.x;
  int swz = ((nwg & 7) == 0) ? ((bid & 7) * (nwg >> 3) + (bid >> 3)) : bid;
  const int bxi = swz % gxc, byi = swz / gxc;
  const int bm = byi * 128, bn = bxi * 128;
  const int tid  = threadIdx.x;
  const int lane = tid & 63, wave = tid >> 6;
  const int wr = wave >> 1, wc = wave & 1;
  const int lr = lane & 15, lk = lane >> 4;
  const int srow = wave * 16 + (lane >> 2);
  const int skc  = (lane & 3) * 8;
  int ar0 = bm + srow;      if (ar0 >= M) ar0 = M - 1;
  int ar1 = bm + srow + 64; if (ar1 >= M) ar1 = M - 1;
  const unsigned short* ga0 = A  + (size_t)ar0 * K + skc;
  const unsigned short* ga1 = A  + (size_t)ar1 * K + skc;
  const unsigned short* gb0 = Bt + (size_t)(bn + srow) * K + skc;
  const unsigned short* gb1 = Bt + (size_t)(bn + srow + 64) * K + skc;
  f32x4 acc[4][4] = {};
  for (int k0 = 0; k0 < K; k0 += 32){
    gld16(ga0 + k0, &As[(size_t)wave * 512]);
    gld16(ga1 + k0, &As[(size_t)(wave + 4) * 512]);
    gld16(gb0 + k0, &Bs[(size_t)wave * 512]);
    gld16(gb1 + k0, &Bs[(size_t)(wave + 4) * 512]);
    __syncthreads();
    short8 af[4], bg[4];
    #pragma unroll
    for (int m = 0; m < 4; ++m)
      af[m] = *reinterpret_cast<const short8*>(&As[(wr * 64 + m * 16 + lr) * 32 + lk * 8]);
    #pragma unroll
    for (int n = 0; n < 4; ++n)
      bg[n] = *reinterpret_cast<const short8*>(&Bs[(wc * 64 + n * 16 + lr) * 32 + lk * 8]);
    #pragma unroll
    for (int m = 0; m < 4; ++m)
      #pragma unroll
      for (int n = 0; n < 4; ++n)
        acc[m][n] = __builtin_amdgcn_mfma_f32_16x16x32_bf16(af[m], bg[n], acc[m][n], 0, 0, 0);
    __syncthreads();
  }
  #pragma unroll
  for (int m = 0; m < 4; ++m){
    #pragma unroll
    for (int j = 0; j < 4; ++j){
      int rowi = bm + wr * 64 + m * 16 + lk * 4 + j;
      if (rowi < M){
        #pragma unroll
        for (int n = 0; n < 4; ++n)
          C[(size_t)rowi * N + bn + wc * 64 + n * 16 + lr] = f2bf(acc[m][n][j]);
      }
    }
  }
}

// ---------------- attention logits from bf16 features ----------------
template<int HEADS, int NPB>
__global__ void k_logits_bf(const unsigned short* __restrict__ hp, const float* __restrict__ a_s,
                            const float* __restrict__ a_d, float* __restrict__ al_s,
                            float* __restrict__ al_d, int N){
  int t = threadIdx.x;
  int node = blockIdx.x * NPB + t / (HEADS * 16);
  if (node >= N) return;
  int r = t % (HEADS * 16);
  int h = r >> 4, lane = r & 15;
  short8 hv8 = *reinterpret_cast<const short8*>(hp + ((size_t)node * HEADS + h) * 128 + lane * 8);
  const float* as = a_s + h * 128 + lane * 8;
  const float* ad = a_d + h * 128 + lane * 8;
  float ss = 0.f, sd = 0.f;
  #pragma unroll
  for (int i = 0; i < 8; ++i){
    float hv = bf2f((unsigned short)hv8[i]);
    ss = fmaf(hv, as[i], ss);
    sd = fmaf(hv, ad[i], sd);
  }
  #pragma unroll
  for (int off = 8; off >= 1; off >>= 1){
    ss += __shfl_xor(ss, off);
    sd += __shfl_xor(sd, off);
  }
  if (lane == 0){
    al_s[(size_t)node * HEADS + h] = ss;
    al_d[(size_t)node * HEADS + h] = sd;
  }
}

// ---------------- GAT aggregation from bf16 features ----------------
template<int HEADS, int VEC, int OUTBF>
__global__ void k_gat_bf(const unsigned short* __restrict__ hp, const float* __restrict__ al_s,
                         const float* __restrict__ al_d, const int* __restrict__ row,
                         const int* __restrict__ csr, const float* __restrict__ bias,
                         void* __restrict__ outv, int N, int do_relu){
  constexpr int TPH = 128 / VEC;
  int n = blockIdx.x;
  int t = threadIdx.x;               // HEADS * TPH
  int h = t / TPH;
  int c0 = (t % TPH) * VEC;
  float ald = al_d[(size_t)n * HEADS + h];
  float m = lrelu(al_s[(size_t)n * HEADS + h] + ald);  // self-loop init (weight exp(0)=1)
  float l = 1.f;
  float acc[VEC];
  const unsigned short* hpn = hp + ((size_t)n * HEADS + h) * 128 + c0;
  if constexpr (VEC == 8){
    short8 hv8 = *reinterpret_cast<const short8*>(hpn);
    #pragma unroll
    for (int v = 0; v < 8; ++v) acc[v] = bf2f((unsigned short)hv8[v]);
  } else {
    ushort2 hv2 = *reinterpret_cast<const ushort2*>(hpn);
    acc[0] = bf2f(hv2.x); acc[1] = bf2f(hv2.y);
  }
  int beg = row[n], end = row[n + 1];
  for (int j = beg; j < end; ++j){
    int s = csr[j];
    float e = lrelu(al_s[(size_t)s * HEADS + h] + ald);
    float mn = fmaxf(m, e);
    float scale = __expf(m - mn);
    float p = __expf(e - mn);
    const unsigned short* hps = hp + ((size_t)s * HEADS + h) * 128 + c0;
    if constexpr (VEC == 8){
      short8 hv8 = *reinterpret_cast<const short8*>(hps);
      #pragma unroll
      for (int v = 0; v < 8; ++v) acc[v] = acc[v] * scale + p * bf2f((unsigned short)hv8[v]);
    } else {
      ushort2 hv2 = *reinterpret_cast<const ushort2*>(hps);
      acc[0] = acc[0] * scale + p * bf2f(hv2.x);
      acc[1] = acc[1] * scale + p * bf2f(hv2.y);
    }
    l = l * scale + p;
    m = mn;
  }
  float inv = 1.f / l;
  size_t ob = ((size_t)n * HEADS + h) * 128 + c0;
  #pragma unroll
  for (int v = 0; v < VEC; ++v){
    float o = acc[v] * inv + bias[h * 128 + c0 + v];
    if (do_relu) o = fmaxf(o, 0.f);
    if constexpr (OUTBF) ((unsigned short*)outv)[ob + v] = f2bf(o);
    else                 ((float*)outv)[ob + v] = o;
  }
}

// ---------------- MLP scorer: [B,256] -> 128 -> 64 -> 1 -> sigmoid ----------------
__global__ void k_mlp(const float* __restrict__ h3, const int* __restrict__ liq,
                      const int* __restrict__ ing,
                      const float* __restrict__ mw1, const float* __restrict__ mb1,
                      const float* __restrict__ mw2, const float* __restrict__ mb2,
                      const float* __restrict__ mw3, const float* __restrict__ mb3,
                      float* __restrict__ out, int B){
  __shared__ float pairv[256];
  __shared__ float z1[128];
  __shared__ float z2[64];
  int r = blockIdx.x;
  int t = threadIdx.x; // 128
  pairv[t]       = h3[(size_t)liq[r] * 128 + t];
  pairv[128 + t] = h3[(size_t)ing[r] * 128 + t];
  __syncthreads();
  float a1 = mb1[t];
  for (int k = 0; k < 256; ++k) a1 = fmaf(pairv[k], mw1[k * 128 + t], a1);
  z1[t] = fmaxf(a1, 0.f);
  __syncthreads();
  if (t < 64){
    float a2 = mb2[t];
    for (int k = 0; k < 128; ++k) a2 = fmaf(z1[k], mw2[k * 64 + t], a2);
    z2[t] = fmaxf(a2, 0.f);
  }
  __syncthreads();
  if (t < 64){
    float p = z2[t] * mw3[t];
    #pragma unroll
    for (int off = 32; off >= 1; off >>= 1) p += __shfl_xor(p, off);
    if (t == 0) out[r] = 1.f / (1.f + __expf(-(p + mb3[0])));
  }
}

// ---------------- launch ----------------
extern "C" void kernel_launch(void* const* d_in, const int* in_sizes, int n_in,
                              void* d_out, int out_size, void* d_ws, size_t ws_size,
                              hipStream_t stream){
  const float* x   = (const float*)d_in[0];
  const int*   ei  = (const int*)  d_in[1];
  const int*   liq = (const int*)  d_in[2];
  const int*   ing = (const int*)  d_in[3];
  const float* W1  = (const float*)d_in[4];
  const float* as1 = (const float*)d_in[5];
  const float* ad1 = (const float*)d_in[6];
  const float* b1  = (const float*)d_in[7];
  const float* W2  = (const float*)d_in[8];
  const float* as2 = (const float*)d_in[9];
  const float* ad2 = (const float*)d_in[10];
  const float* b2  = (const float*)d_in[11];
  const float* W3  = (const float*)d_in[12];
  const float* as3 = (const float*)d_in[13];
  const float* ad3 = (const float*)d_in[14];
  const float* b3  = (const float*)d_in[15];
  const float* mw1 = (const float*)d_in[16];
  const float* mb1 = (const float*)d_in[17];
  const float* mw2 = (const float*)d_in[18];
  const float* mb2 = (const float*)d_in[19];
  const float* mw3 = (const float*)d_in[20];
  const float* mb3 = (const float*)d_in[21];
  float* out = (float*)d_out;

  const int N = in_sizes[0] / 64;      // 25000
  const int E = in_sizes[1] / 2;       // 200000
  const int B = in_sizes[2];           // 4096
  const int* srcp = ei;
  const int* dstp = ei + E;

  // workspace carve-up
  char* w = (char*)d_ws;
  auto alloc = [&](size_t bytes) -> char* {
    char* p = w;
    w += (bytes + 255) & ~(size_t)255;
    return p;
  };
  unsigned short* P    = (unsigned short*)alloc((size_t)N * 1024 * 2);  // projected feats bf16
  unsigned short* Hb   = (unsigned short*)alloc((size_t)N * 1024 * 2);  // node feats bf16
  float*          H3   = (float*)         alloc((size_t)N * 128 * 4);   // layer-3 out fp32
  unsigned short* xb   = (unsigned short*)alloc((size_t)N * 64 * 2);
  unsigned short* Wt1  = (unsigned short*)alloc((size_t)1024 * 64 * 2);
  unsigned short* Wt2  = (unsigned short*)alloc((size_t)1024 * 1024 * 2);
  unsigned short* Wt3  = (unsigned short*)alloc((size_t)128 * 1024 * 2);
  float* ALS  = (float*)alloc((size_t)N * 8 * 4);
  float* ALD  = (float*)alloc((size_t)N * 8 * 4);
  int*   row  = (int*)  alloc((size_t)(N + 1) * 4);
  int*   cnt  = (int*)  alloc((size_t)N * 4);
  int*   cur  = (int*)  alloc((size_t)N * 4);
  int*   aux  = (int*)  alloc((size_t)256 * 4);
  int*   csr  = (int*)  alloc((size_t)E * 4);
  (void)ws_size; (void)n_in; (void)out_size;

  // conversions
  int nx = N * 64;
  k_f2bf<<<(nx + 255) / 256, 256, 0, stream>>>(x, xb, nx);
  k_transpose_bf16<<<dim3(64/32, 1024/32), 256, 0, stream>>>(W1, Wt1, 64, 1024);
  k_transpose_bf16<<<dim3(1024/32, 1024/32), 256, 0, stream>>>(W2, Wt2, 1024, 1024);
  k_transpose_bf16<<<dim3(1024/32, 128/32), 256, 0, stream>>>(W3, Wt3, 1024, 128);

  // CSR build (parallel scan)
  hipMemsetAsync(cnt, 0, (size_t)N * 4, stream);
  hipMemsetAsync(cur, 0, (size_t)N * 4, stream);
  int eb = (E + 255) / 256;
  int nb = (N + 255) / 256;            // 98 blocks
  k_count<<<eb, 256, 0, stream>>>(dstp, cnt, E);
  k_blockscan<<<nb, 256, 0, stream>>>(cnt, row, aux, N);
  k_scanaux<<<1, 256, 0, stream>>>(aux, nb);
  k_addoff<<<nb, 256, 0, stream>>>(aux, row, N);
  k_scatter<<<eb, 256, 0, stream>>>(srcp, dstp, row, cur, csr, E);

  const int mt = (N + 127) / 128;      // 196

  // ---- layer 1: x[N,64] @ W1[64,1024] ----
  k_gemm_bf16<<<8 * mt, 256, 0, stream>>>(xb, Wt1, P, N, 1024, 64, 8);
  k_logits_bf<8,2><<<(N + 1) / 2, 256, 0, stream>>>(P, as1, ad1, ALS, ALD, N);
  k_gat_bf<8,8,1><<<N, 128, 0, stream>>>(P, ALS, ALD, row, csr, b1, Hb, N, 1);

  // ---- layer 2: Hb[N,1024] @ W2[1024,1024] ----
  k_gemm_bf16<<<8 * mt, 256, 0, stream>>>(Hb, Wt2, P, N, 1024, 1024, 8);
  k_logits_bf<8,2><<<(N + 1) / 2, 256, 0, stream>>>(P, as2, ad2, ALS, ALD, N);
  k_gat_bf<8,8,1><<<N, 128, 0, stream>>>(P, ALS, ALD, row, csr, b2, Hb, N, 1);

  // ---- layer 3: Hb[N,1024] @ W3[1024,128] (1 head) ----
  k_gemm_bf16<<<1 * mt, 256, 0, stream>>>(Hb, Wt3, P, N, 128, 1024, 1);
  k_logits_bf<1,16><<<(N + 15) / 16, 256, 0, stream>>>(P, as3, ad3, ALS, ALD, N);
  k_gat_bf<1,2,0><<<N, 64, 0, stream>>>(P, ALS, ALD, row, csr, b3, H3, N, 0);

  // ---- MLP scorer ----
  k_mlp<<<B, 128, 0, stream>>>(H3, liq, ing, mw1, mb1, mw2, mb2, mw3, mb3, out, B);
}